// Round 2
// baseline (591.815 us; speedup 1.0000x reference)
//
#include <hip/hip_runtime.h>
#include <hip/hip_bf16.h>
#include <stdint.h>

#define IN_F  4096
#define OUT_F 4096
#define BSZ   4
#define SEQ   2048
#define MDIM  (BSZ * SEQ)   // 8192

// ---------------- address-space helpers for global_load_lds ----------------
typedef __attribute__((address_space(1))) uint8_t ga_u8_t;
typedef __attribute__((address_space(3))) uint8_t ls_u8_t;

__device__ __forceinline__ void gload16_lds(const void* g, void* l) {
    // 16B-wide direct global->LDS DMA (global_load_lds_dwordx4)
    __builtin_amdgcn_global_load_lds((ga_u8_t*)g, (ls_u8_t*)l, 16, 0, 0);
}

// round-to-nearest-even fp32 -> bf16, returned as fp32 value
__device__ __forceinline__ float bf16_rne(float f) {
    unsigned u = __float_as_uint(f);
    u = (u + 0x7fffu + ((u >> 16) & 1u)) & 0xffff0000u;
    return __uint_as_float(u);
}

// ---------------- pass 1: global amax of |x| ----------------
__global__ void amax_kernel(const float* __restrict__ x, int n4,
                            unsigned int* __restrict__ amax_u) {
    const float4* x4 = (const float4*)x;
    int idx = blockIdx.x * blockDim.x + threadIdx.x;
    int stride = gridDim.x * blockDim.x;
    float m = 0.0f;
    for (int i = idx; i < n4; i += stride) {
        float4 v = x4[i];
        m = fmaxf(m, fmaxf(fmaxf(fabsf(v.x), fabsf(v.y)),
                           fmaxf(fabsf(v.z), fabsf(v.w))));
    }
    for (int off = 32; off > 0; off >>= 1)
        m = fmaxf(m, __shfl_down(m, off, 64));
    __shared__ float sm[4];
    int lane = threadIdx.x & 63, wave = threadIdx.x >> 6;
    if (lane == 0) sm[wave] = m;
    __syncthreads();
    if (threadIdx.x == 0) {
        m = fmaxf(fmaxf(sm[0], sm[1]), fmaxf(sm[2], sm[3]));
        atomicMax(amax_u, __float_as_uint(m));  // valid: all values >= 0
    }
}

// ---------------- pass 2: quantize x -> int8 AND repack w -> int8 ----------
__global__ void prep_kernel(const float* __restrict__ x,
                            const int* __restrict__ w,
                            signed char* __restrict__ x8,
                            signed char* __restrict__ w8,
                            const unsigned int* __restrict__ amax_u,
                            int nx4, int nw4) {
    int idx = blockIdx.x * blockDim.x + threadIdx.x;
    if (idx < nx4) {
        float amax = __uint_as_float(*amax_u);
        float xs = (amax == 0.0f) ? 1.0f : (amax / 127.0f);  // ref: amax/127
        float4 v = ((const float4*)x)[idx];
        char4 q;
        q.x = (signed char)fminf(fmaxf(rintf(v.x / xs), -127.0f), 127.0f);
        q.y = (signed char)fminf(fmaxf(rintf(v.y / xs), -127.0f), 127.0f);
        q.z = (signed char)fminf(fmaxf(rintf(v.z / xs), -127.0f), 127.0f);
        q.w = (signed char)fminf(fmaxf(rintf(v.w / xs), -127.0f), 127.0f);
        ((char4*)x8)[idx] = q;
    } else {
        int widx = idx - nx4;
        if (widx < nw4) {
            int4 v = ((const int4*)w)[widx];
            char4 q;
            q.x = (signed char)v.x; q.y = (signed char)v.y;
            q.z = (signed char)v.z; q.w = (signed char)v.w;
            ((char4*)w8)[widx] = q;
        }
    }
}

// ---------------- pass 3: int8 GEMM (32x32x32 MFMA) + bf16 epilogue -------
// A = x_int8 [M, K] row-major, B = w_int8 [N, K] row-major (B^T GEMM).
// Tile 128x128, BK=128, 4 waves in 2x2, each wave 64x64 = 2x2 of 32x32x32.
// LDS chunk-major layout: granule index G = chunk*128 + row; LDS addr = G*16.
// (chunk = k-byte/16 within the BK=128 slab). Staging writes G = t + 256*s,
// contiguous per wave, exactly what global_load_lds requires; fragment reads
// (fixed chunk, rows 0..31 per half-wave) are 512B-contiguous -> conflict-free.
using i32x4 = __attribute__((ext_vector_type(4))) int;
using i32x16 = __attribute__((ext_vector_type(16))) int;

__global__ __launch_bounds__(256, 4) void gemm_i8_kernel(
    const signed char* __restrict__ A,
    const signed char* __restrict__ B,
    const unsigned int* __restrict__ amax_u,
    const float* __restrict__ wscale_p,
    const float* __restrict__ bias,
    float* __restrict__ out) {
    __shared__ signed char sA[128 * 128];
    __shared__ signed char sB[128 * 128];

    const int t = threadIdx.x;
    const int lane = t & 63;
    const int wave = t >> 6;
    const int wm = wave >> 1;
    const int wn = wave & 1;
    const int tileM = blockIdx.y * 128;
    const int tileN = blockIdx.x * 128;

    // staging addresses: granule G = t + 256*s; row = G&127, chunk = G>>7
    const signed char* gA[4];
    const signed char* gB[4];
    signed char* lA[4];
    signed char* lB[4];
#pragma unroll
    for (int s = 0; s < 4; ++s) {
        int G = t + 256 * s;
        int row = G & 127, ch = G >> 7;
        gA[s] = A + (size_t)(tileM + row) * IN_F + ch * 16;
        gB[s] = B + (size_t)(tileN + row) * IN_F + ch * 16;
        lA[s] = sA + G * 16;
        lB[s] = sB + G * 16;
    }

    // fragment LDS offsets: frag i: row = w*64 + i*32 + (lane&31),
    // k-half h = lane>>5 -> offset = (h*128 + row)*16 ; + ks*4096 per k-step
    int aoff[2], boff[2];
#pragma unroll
    for (int i = 0; i < 2; ++i) {
        aoff[i] = (((lane >> 5) * 128) + wm * 64 + i * 32 + (lane & 31)) * 16;
        boff[i] = (((lane >> 5) * 128) + wn * 64 + i * 32 + (lane & 31)) * 16;
    }

    i32x16 acc[2][2] = {};

    for (int k0 = 0; k0 < IN_F; k0 += 128) {
        __syncthreads();  // previous compute done before LDS overwrite
#pragma unroll
        for (int s = 0; s < 4; ++s) {
            gload16_lds(gA[s] + k0, lA[s]);
            gload16_lds(gB[s] + k0, lB[s]);
        }
        __syncthreads();  // staging drained (vmcnt(0))

#pragma unroll
        for (int ks = 0; ks < 4; ++ks) {
            i32x4 aF[2], bF[2];
#pragma unroll
            for (int i = 0; i < 2; ++i)
                aF[i] = *(const i32x4*)(sA + ks * 4096 + aoff[i]);
#pragma unroll
            for (int j = 0; j < 2; ++j)
                bF[j] = *(const i32x4*)(sB + ks * 4096 + boff[j]);
#pragma unroll
            for (int i = 0; i < 2; ++i)
#pragma unroll
                for (int j = 0; j < 2; ++j)
                    acc[i][j] = __builtin_amdgcn_mfma_i32_32x32x32_i8(
                        aF[i], bF[j], acc[i][j], 0, 0, 0);
        }
    }

    // Epilogue: out = fp32( bf16(acc) * bf16(xs*ws) ) + bias
    float amax = __uint_as_float(*amax_u);
    float xs = (amax == 0.0f) ? 1.0f : (amax / 127.0f);
    float cs = bf16_rne(xs * wscale_p[0]);

    // C/D layout (32x32, verified m74/m101): col = lane&31,
    // row = 4*(lane>>5) + (reg&3) + 8*(reg>>2)
#pragma unroll
    for (int j = 0; j < 2; ++j) {
        int n = tileN + wn * 64 + j * 32 + (lane & 31);
        float bz = bias[n];
#pragma unroll
        for (int i = 0; i < 2; ++i) {
            int rbase = tileM + wm * 64 + i * 32 + 4 * (lane >> 5);
#pragma unroll
            for (int r = 0; r < 16; ++r) {
                int row = rbase + (r & 3) + 8 * (r >> 2);
                float v = bf16_rne((float)acc[i][j][r]);
                float p = bf16_rne(v * cs);
                out[(size_t)row * OUT_F + n] = p + bz;
            }
        }
    }
}

// ---------------- launch ----------------
extern "C" void kernel_launch(void* const* d_in, const int* in_sizes, int n_in,
                              void* d_out, int out_size, void* d_ws,
                              size_t ws_size, hipStream_t stream) {
    const float* x = (const float*)d_in[0];
    const int* w_int = (const int*)d_in[1];
    const float* w_scale = (const float*)d_in[2];
    const float* bias = (const float*)d_in[3];
    float* out = (float*)d_out;

    unsigned char* ws = (unsigned char*)d_ws;
    unsigned int* amax_u = (unsigned int*)ws;                         // 4 B
    signed char* w8 = (signed char*)(ws + 64);                        // 16 MiB
    signed char* x8 = (signed char*)(ws + 64 + (size_t)OUT_F * IN_F); // 32 MiB

    hipMemsetAsync(amax_u, 0, 4, stream);

    const int n_x4 = MDIM * IN_F / 4;   // 8,388,608 float4
    const int n_w4 = OUT_F * IN_F / 4;  // 4,194,304 int4

    amax_kernel<<<4096, 256, 0, stream>>>(x, n_x4, amax_u);
    prep_kernel<<<(n_x4 + n_w4) / 256, 256, 0, stream>>>(
        x, w_int, x8, w8, amax_u, n_x4, n_w4);

    dim3 grid(OUT_F / 128, MDIM / 128);  // (32, 64)
    gemm_i8_kernel<<<grid, 256, 0, stream>>>(x8, w8, amax_u, w_scale, bias, out);
}

// Round 3
// 459.339 us; speedup vs baseline: 1.2884x; 1.2884x over previous
//
#include <hip/hip_runtime.h>
#include <hip/hip_bf16.h>
#include <stdint.h>

#define IN_F  4096
#define OUT_F 4096
#define BSZ   4
#define SEQ   2048
#define MDIM  (BSZ * SEQ)   // 8192

// ---------------- address-space helpers for global_load_lds ----------------
typedef __attribute__((address_space(1))) uint8_t ga_u8_t;
typedef __attribute__((address_space(3))) uint8_t ls_u8_t;

__device__ __forceinline__ void gload16_lds(const void* g, void* l) {
    // 16B-wide direct global->LDS DMA (global_load_lds_dwordx4)
    __builtin_amdgcn_global_load_lds((ga_u8_t*)g, (ls_u8_t*)l, 16, 0, 0);
}

// round-to-nearest-even fp32 -> bf16, returned as fp32 value
__device__ __forceinline__ float bf16_rne(float f) {
    unsigned u = __float_as_uint(f);
    u = (u + 0x7fffu + ((u >> 16) & 1u)) & 0xffff0000u;
    return __uint_as_float(u);
}

// ---------------- pass 1: global amax of |x| ----------------
__global__ void amax_kernel(const float* __restrict__ x, int n4,
                            unsigned int* __restrict__ amax_u) {
    const float4* x4 = (const float4*)x;
    int idx = blockIdx.x * blockDim.x + threadIdx.x;
    int stride = gridDim.x * blockDim.x;
    float m = 0.0f;
    for (int i = idx; i < n4; i += stride) {
        float4 v = x4[i];
        m = fmaxf(m, fmaxf(fmaxf(fabsf(v.x), fabsf(v.y)),
                           fmaxf(fabsf(v.z), fabsf(v.w))));
    }
    for (int off = 32; off > 0; off >>= 1)
        m = fmaxf(m, __shfl_down(m, off, 64));
    __shared__ float sm[4];
    int lane = threadIdx.x & 63, wave = threadIdx.x >> 6;
    if (lane == 0) sm[wave] = m;
    __syncthreads();
    if (threadIdx.x == 0) {
        m = fmaxf(fmaxf(sm[0], sm[1]), fmaxf(sm[2], sm[3]));
        atomicMax(amax_u, __float_as_uint(m));  // valid: all values >= 0
    }
}

// ---------------- pass 2: quantize x -> int8 AND repack w -> int8 ----------
__global__ void prep_kernel(const float* __restrict__ x,
                            const int* __restrict__ w,
                            signed char* __restrict__ x8,
                            signed char* __restrict__ w8,
                            const unsigned int* __restrict__ amax_u,
                            int nx4, int nw4) {
    int idx = blockIdx.x * blockDim.x + threadIdx.x;
    if (idx < nx4) {
        float amax = __uint_as_float(*amax_u);
        float xs = (amax == 0.0f) ? 1.0f : (amax / 127.0f);  // ref: amax/127
        float4 v = ((const float4*)x)[idx];
        char4 q;
        q.x = (signed char)fminf(fmaxf(rintf(v.x / xs), -127.0f), 127.0f);
        q.y = (signed char)fminf(fmaxf(rintf(v.y / xs), -127.0f), 127.0f);
        q.z = (signed char)fminf(fmaxf(rintf(v.z / xs), -127.0f), 127.0f);
        q.w = (signed char)fminf(fmaxf(rintf(v.w / xs), -127.0f), 127.0f);
        ((char4*)x8)[idx] = q;
    } else {
        int widx = idx - nx4;
        if (widx < nw4) {
            int4 v = ((const int4*)w)[widx];
            char4 q;
            q.x = (signed char)v.x; q.y = (signed char)v.y;
            q.z = (signed char)v.z; q.w = (signed char)v.w;
            ((char4*)w8)[widx] = q;
        }
    }
}

// ---------------- pass 3: int8 GEMM (MFMA 16x16x64) + bf16 epilogue -------
// A = x_int8 [M, K] row-major, B = w_int8 [N, K] row-major (B^T GEMM).
// Tile 128x128, BK=64, 4 waves in 2x2, each wave 4x4 subtiles of 16x16x64.
// R1 core (184 us, MfmaUtil 33%); R2's 32x32/BK=128 restructure regressed
// (too few independent MFMAs between accumulator reuses) -- do not repeat.
using i32x4 = __attribute__((ext_vector_type(4))) int;

__global__ __launch_bounds__(256, 2) void gemm_i8_kernel(
    const signed char* __restrict__ A,
    const signed char* __restrict__ B,
    const unsigned int* __restrict__ amax_u,
    const float* __restrict__ wscale_p,
    const float* __restrict__ bias,
    float* __restrict__ out) {
    __shared__ signed char sA[128 * 64];
    __shared__ signed char sB[128 * 64];

    const int t = threadIdx.x;
    const int lane = t & 63;
    const int wave = t >> 6;
    const int wm = wave >> 1;
    const int wn = wave & 1;

    // Swizzled 1D grid: groups of 256 blocks = 8 M-tiles x 32 N-tiles.
    // Co-resident working set: A 8x512KB=4MB + B 16MB -> fits aggregate L2.
    const int bid = blockIdx.x;
    const int mt = (bid >> 8) * 8 + (bid & 7);
    const int nt = (bid & 255) >> 3;
    const int tileM = mt * 128;
    const int tileN = nt * 128;

    // Staging: granule g (16B) -> LDS slot g*16 (contiguous, lane-order,
    // as global_load_lds requires). Data placed with XOR swizzle on the
    // 4 column-granules: slot (row, c) holds global (row, c ^ ((row>>1)&3)).
    const int g0 = t, g1 = t + 256;
    const int ar0 = g0 >> 2, ac0 = ((g0 & 3) ^ ((ar0 >> 1) & 3)) * 16;
    const int ar1 = g1 >> 2, ac1 = ((g1 & 3) ^ ((ar1 >> 1) & 3)) * 16;

    const signed char* gA0 = A + (size_t)(tileM + ar0) * IN_F + ac0;
    const signed char* gA1 = A + (size_t)(tileM + ar1) * IN_F + ac1;
    const signed char* gB0 = B + (size_t)(tileN + ar0) * IN_F + ac0;
    const signed char* gB1 = B + (size_t)(tileN + ar1) * IN_F + ac1;

    signed char* lA0 = sA + g0 * 16;
    signed char* lA1 = sA + g1 * 16;
    signed char* lB0 = sB + g0 * 16;
    signed char* lB1 = sB + g1 * 16;

    i32x4 acc[4][4] = {};

    // Fragment LDS read addresses (fixed across K iterations).
    // A fragment: m = lane&15, k-chunk = lane>>4 (same chunking for B ->
    // intra-fragment k permutation cancels between A and B).
    const signed char* aptr[4];
    const signed char* bptr[4];
#pragma unroll
    for (int i = 0; i < 4; ++i) {
        int rowa = wm * 64 + i * 16 + (lane & 15);
        int ca = ((lane >> 4) ^ ((rowa >> 1) & 3)) * 16;
        aptr[i] = sA + rowa * 64 + ca;
        int rowb = wn * 64 + i * 16 + (lane & 15);
        int cb = ((lane >> 4) ^ ((rowb >> 1) & 3)) * 16;
        bptr[i] = sB + rowb * 64 + cb;
    }

    for (int k0 = 0; k0 < IN_F; k0 += 64) {
        __syncthreads();  // previous compute done before LDS overwrite
        gload16_lds(gA0 + k0, lA0);
        gload16_lds(gA1 + k0, lA1);
        gload16_lds(gB0 + k0, lB0);
        gload16_lds(gB1 + k0, lB1);
        __syncthreads();  // drains vmcnt(0): staging complete

        i32x4 aF[4], bF[4];
#pragma unroll
        for (int i = 0; i < 4; ++i) aF[i] = *(const i32x4*)aptr[i];
#pragma unroll
        for (int j = 0; j < 4; ++j) bF[j] = *(const i32x4*)bptr[j];
#pragma unroll
        for (int i = 0; i < 4; ++i)
#pragma unroll
            for (int j = 0; j < 4; ++j)
                acc[i][j] = __builtin_amdgcn_mfma_i32_16x16x64_i8(
                    aF[i], bF[j], acc[i][j], 0, 0, 0);
    }

    // Epilogue: out = fp32( bf16(acc) * bf16(xs*ws) ) + bias
    float amax = __uint_as_float(*amax_u);
    float xs = (amax == 0.0f) ? 1.0f : (amax / 127.0f);
    float cs = bf16_rne(xs * wscale_p[0]);

    // C/D layout (16x16): col = lane&15, row = (lane>>4)*4 + reg
#pragma unroll
    for (int j = 0; j < 4; ++j) {
        int n = tileN + wn * 64 + j * 16 + (lane & 15);
        float bz = bias[n];
#pragma unroll
        for (int i = 0; i < 4; ++i) {
            int row0 = tileM + wm * 64 + i * 16 + (lane >> 4) * 4;
#pragma unroll
            for (int r = 0; r < 4; ++r) {
                float v = bf16_rne((float)acc[i][j][r]);
                float p = bf16_rne(v * cs);
                // nontemporal: don't let the 128MB output evict A/B in L2/LLC
                __builtin_nontemporal_store(
                    p + bz, &out[(size_t)(row0 + r) * OUT_F + n]);
            }
        }
    }
}

// ---------------- launch ----------------
extern "C" void kernel_launch(void* const* d_in, const int* in_sizes, int n_in,
                              void* d_out, int out_size, void* d_ws,
                              size_t ws_size, hipStream_t stream) {
    const float* x = (const float*)d_in[0];
    const int* w_int = (const int*)d_in[1];
    const float* w_scale = (const float*)d_in[2];
    const float* bias = (const float*)d_in[3];
    float* out = (float*)d_out;

    unsigned char* ws = (unsigned char*)d_ws;
    unsigned int* amax_u = (unsigned int*)ws;                         // 4 B
    signed char* w8 = (signed char*)(ws + 64);                        // 16 MiB
    signed char* x8 = (signed char*)(ws + 64 + (size_t)OUT_F * IN_F); // 32 MiB

    hipMemsetAsync(amax_u, 0, 4, stream);

    const int n_x4 = MDIM * IN_F / 4;   // 8,388,608 float4
    const int n_w4 = OUT_F * IN_F / 4;  // 4,194,304 int4

    amax_kernel<<<4096, 256, 0, stream>>>(x, n_x4, amax_u);
    prep_kernel<<<(n_x4 + n_w4) / 256, 256, 0, stream>>>(
        x, w_int, x8, w8, amax_u, n_x4, n_w4);

    const int nblocks = (MDIM / 128) * (OUT_F / 128);  // 2048
    gemm_i8_kernel<<<nblocks, 256, 0, stream>>>(x8, w8, amax_u, w_scale, bias,
                                                out);
}